// Round 5
// baseline (298.462 us; speedup 1.0000x reference)
//
#include <hip/hip_runtime.h>

// ---------------------------------------------------------------------------
// Attention (ViT-style, B=32, N=577, C=768), fp32 in/out, bf16 MFMA compute.
//
//   k_cvt3     : x, w_qkv, w_proj  fp32 -> bf16 (single launch)
//   k_qkv_qk   : q,k tiles: (x @ w^T) -> row-major bf16, GLOBAL M-tiling
//                (145 x 12 tiles; no per-batch padding waste)
//   k_qkv_v    : v tiles OPERAND-SWAPPED: (w_v @ x^T) -> vT [768][32*640]
//                directly in MFMA C-layout (aligned 16B stores)
//   k_logits   : per batch: q_b x k_b^T -> exp2(S*scale) UNNORMALIZED bf16
//                P~ [640,640] (pad cols zeroed, pad rows unwritten) +
//                per-tile row-sum partials.
//   k_pv       : OPERAND-SWAPPED: yT[c][n] = sum_k vt[c,k] * Pt[n,k], with
//                per-column 1/l normalization; natural [m][n] staging.
//                tC==0 blocks also emit token_attn.
//   k_proj     : yT-flat-as-[18464,768] x w_proj^T + b_proj -> out fp32,
//                LDS-staged fp32 epilogue (two 64-row passes, float4 stores).
//
// GEMM core: 128x128 tile, BK=64, 4 waves x (4x4 of 16x16x32 bf16 MFMA),
// global_load_lds width=16 staging, XOR chunk swizzle in LDS, XCD-chunked
// block swizzle. k_qkv_* run at the m97 structural plateau (~870 TF issued).
// Workspace required: 176,242,688 B (~168 MiB).
// ---------------------------------------------------------------------------

typedef __attribute__((ext_vector_type(4))) float f32x4;
typedef __attribute__((ext_vector_type(8))) short short8;
typedef __attribute__((ext_vector_type(8))) unsigned short ushort8v;
typedef __attribute__((ext_vector_type(4))) unsigned short ushort4v;

#define TILE 128
#define BK 64

#define NB 32
#define SEQ 577
#define SEQP 640            // padded seq
#define DIM 768
#define MTOT (NB * SEQ)     // 18464
#define VTLD (NB * SEQP)    // 20480 — vt row stride (vt[c][b*640+nn])
#define KC 0.05205949529797614f   // log2(e) / sqrt(768)

__device__ __forceinline__ unsigned short f2bf(float f) {
  union { float f; unsigned u; } x; x.f = f;
  unsigned r = x.u + 0x7fffu + ((x.u >> 16) & 1u);   // round-to-nearest-even
  return (unsigned short)(r >> 16);
}

__device__ __forceinline__ float bf2f(unsigned short v) {
  union { unsigned u; float f; } x; x.u = ((unsigned)v) << 16; return x.f;
}

__device__ __forceinline__ void gload16(const unsigned short* g, unsigned short* l) {
  __builtin_amdgcn_global_load_lds(
      (const __attribute__((address_space(1))) unsigned int*)g,
      (__attribute__((address_space(3))) unsigned int*)l, 16, 0, 0);
}

// Bijective remap: HW round-robin slot (xcd = lin&7) -> contiguous logical
// block range per XCD, so blocks sharing an A tile stay on one XCD's L2.
__device__ __forceinline__ int swiz(int lin, int nblk) {
  int xcd = lin & 7, pos = lin >> 3;
  int per = nblk >> 3, rem = nblk & 7;
  return xcd * per + (xcd < rem ? xcd : rem) + pos;
}

// C[m,n] = sum_k A[m,k] * B[n,k]   (both row-major, "B-transposed" GEMM)
__device__ __forceinline__ void gemm_core(
    unsigned short* smem,
    const unsigned short* __restrict__ A, int ldA, int rowmaxA, int blkM,
    const unsigned short* __restrict__ B, int ldB, int rowmaxB, int blkN,
    int K, f32x4 acc[4][4])
{
  unsigned short* sA = smem;
  unsigned short* sB = smem + TILE * BK;
  const int t = threadIdx.x;
  const int lane = t & 63;
  const int wave = t >> 6;
  const int wr = (wave >> 1) * 64;
  const int wc = (wave & 1) * 64;
  const int lrow = lane & 15;
  const int quad = lane >> 4;

  for (int k0 = 0; k0 < K; k0 += BK) {
#pragma unroll
    for (int it = 0; it < 4; ++it) {
      int tt = t + it * 256;          // 0..1023 -> 16KB per buffer
      int rr = tt >> 3;               // LDS row 0..127
      int gc = (tt & 7) ^ (rr & 7);   // swizzled source chunk
      int ra = blkM + rr; if (ra > rowmaxA) ra = rowmaxA;
      int rb = blkN + rr; if (rb > rowmaxB) rb = rowmaxB;
      gload16(A + (size_t)ra * ldA + k0 + gc * 8, sA + tt * 8);
      gload16(B + (size_t)rb * ldB + k0 + gc * 8, sB + tt * 8);
    }
    __syncthreads();
#pragma unroll
    for (int kk = 0; kk < 2; ++kk) {
      short8 af[4], bfr[4];
#pragma unroll
      for (int i = 0; i < 4; ++i) {
        int m = wr + i * 16 + lrow;
        af[i] = *(const short8*)(sA + m * BK + (((kk * 4 + quad) ^ (m & 7)) * 8));
      }
#pragma unroll
      for (int j = 0; j < 4; ++j) {
        int n = wc + j * 16 + lrow;
        bfr[j] = *(const short8*)(sB + n * BK + (((kk * 4 + quad) ^ (n & 7)) * 8));
      }
#pragma unroll
      for (int i = 0; i < 4; ++i)
#pragma unroll
        for (int j = 0; j < 4; ++j)
          acc[i][j] = __builtin_amdgcn_mfma_f32_16x16x32_bf16(af[i], bfr[j], acc[i][j], 0, 0, 0);
    }
    __syncthreads();
  }
}

// ---------------------------------------------------------------------------
#define N4X  3545088
#define N4W1 442368
#define N4W2 147456
__global__ __launch_bounds__(256) void k_cvt3(
    const float* __restrict__ x, const float* __restrict__ w1, const float* __restrict__ w2,
    unsigned short* __restrict__ xo, unsigned short* __restrict__ w1o,
    unsigned short* __restrict__ w2o) {
  int i = blockIdx.x * 256 + threadIdx.x;
  const float4* src; ushort4* dst; int off;
  if (i < N4X)                 { src = (const float4*)x;  dst = (ushort4*)xo;  off = i; }
  else if (i < N4X + N4W1)     { src = (const float4*)w1; dst = (ushort4*)w1o; off = i - N4X; }
  else                         { src = (const float4*)w2; dst = (ushort4*)w2o; off = i - N4X - N4W1; }
  float4 v = src[off];
  ushort4 o;
  o.x = f2bf(v.x); o.y = f2bf(v.y); o.z = f2bf(v.z); o.w = f2bf(v.w);
  dst[off] = o;
}

// q,k = x @ w_qkv[0:1536]^T — global M tiling (145 x 12 tiles)
__global__ __launch_bounds__(256, 2) void k_qkv_qk(
    const unsigned short* __restrict__ xb, const unsigned short* __restrict__ wb,
    unsigned short* __restrict__ qb, unsigned short* __restrict__ kb) {
  __shared__ unsigned short smem[2 * TILE * BK];
  f32x4 acc[4][4];
#pragma unroll
  for (int i = 0; i < 4; ++i)
#pragma unroll
    for (int j = 0; j < 4; ++j) acc[i][j] = (f32x4){0.f, 0.f, 0.f, 0.f};

  int lin = swiz(blockIdx.y * 12 + blockIdx.x, 12 * 145);
  const int tN = lin % 12;         // 0..5 -> q, 6..11 -> k
  const int tM = lin / 12;
  const int sel = tN / 6, cbase = (tN % 6) * TILE;
  gemm_core(smem, xb, DIM, MTOT - 1, tM * TILE, wb, DIM, 3 * DIM - 1, tN * TILE, DIM, acc);

  const int t = threadIdx.x, lane = t & 63, wave = t >> 6;
  const int wr = (wave >> 1) * 64, wc = (wave & 1) * 64;
  const int l15 = lane & 15, quad = lane >> 4;

  // stage row-major [m=token][n=channel]
#pragma unroll
  for (int i = 0; i < 4; ++i)
#pragma unroll
    for (int j = 0; j < 4; ++j)
#pragma unroll
      for (int r = 0; r < 4; ++r) {
        int m = wr + i * 16 + quad * 4 + r, n = wc + j * 16 + l15;
        smem[m * TILE + (n ^ ((m & 7) << 3))] = f2bf(acc[i][j][r]);
      }
  __syncthreads();
  unsigned short* dst = sel == 0 ? qb : kb;
#pragma unroll
  for (int s = 0; s < 8; ++s) {
    int idx = t + s * 256, rr = idx >> 4, seg = idx & 15;
    int m = tM * TILE + rr;                          // global token row
    if (m < MTOT) {
      ushort8v v = *(const ushort8v*)(smem + rr * TILE + ((seg * 8) ^ ((rr & 7) << 3)));
      *(ushort8v*)(dst + (size_t)m * DIM + cbase + seg * 8) = v;
    }
  }
}

// vT[c][b*640+n] = sum_k w_v[c,k] * x_b[n,k]   (operand-swapped)
__global__ __launch_bounds__(256, 2) void k_qkv_v(
    const unsigned short* __restrict__ xb, const unsigned short* __restrict__ wb,
    unsigned short* __restrict__ vt) {
  __shared__ unsigned short smem[2 * TILE * BK];
  f32x4 acc[4][4];
#pragma unroll
  for (int i = 0; i < 4; ++i)
#pragma unroll
    for (int j = 0; j < 4; ++j) acc[i][j] = (f32x4){0.f, 0.f, 0.f, 0.f};

  int lin = swiz(blockIdx.y * 6 + blockIdx.x, 6 * 160);
  const int ct = lin % 6;          // channel tile
  const int rest = lin / 6;
  const int b = rest / 5, mt = rest % 5;
  const unsigned short* Xb = xb + (size_t)b * SEQ * DIM;
  gemm_core(smem, wb, DIM, 3 * DIM - 1, 2 * DIM + ct * TILE, Xb, DIM, SEQ - 1, mt * TILE, DIM, acc);

  const int t = threadIdx.x, lane = t & 63, wave = t >> 6;
  const int wr = (wave >> 1) * 64, wc = (wave & 1) * 64;
  const int l15 = lane & 15, quad = lane >> 4;

  // stage row-major [m=channel][n=token]
#pragma unroll
  for (int i = 0; i < 4; ++i)
#pragma unroll
    for (int j = 0; j < 4; ++j)
#pragma unroll
      for (int r = 0; r < 4; ++r) {
        int m = wr + i * 16 + quad * 4 + r, n = wc + j * 16 + l15;
        smem[m * TILE + (n ^ ((m & 7) << 3))] = f2bf(acc[i][j][r]);
      }
  __syncthreads();
#pragma unroll
  for (int s = 0; s < 8; ++s) {
    int idx = t + s * 256, rr = idx >> 4, seg = idx & 15;
    int c = ct * TILE + rr;
    int n0 = mt * TILE + seg * 8;                    // token within batch
    if (n0 < SEQ) {
      ushort8v v = *(const ushort8v*)(smem + rr * TILE + ((seg * 8) ^ ((rr & 7) << 3)));
      unsigned short* dp = vt + (size_t)c * VTLD + (size_t)b * SEQP + n0;
      if (n0 + 8 <= SEQ) *(ushort8v*)dp = v;         // 16B-aligned always
      else {
#pragma unroll
        for (int e = 0; e < 8; ++e) if (n0 + e < SEQ) dp[e] = v[e];
      }
    }
  }
}

// P~ = exp2(q_b @ k_b^T * KC) unnormalized, bf16 (pad cols zeroed, pad rows
// unwritten), plus per-tile row-sum partials part[b][tN][row] (rows < SEQ).
__global__ __launch_bounds__(256, 2) void k_logits(
    const unsigned short* __restrict__ qb, const unsigned short* __restrict__ kb,
    unsigned short* __restrict__ Pt, float* __restrict__ part) {
  __shared__ unsigned short smem[2 * TILE * BK];
  __shared__ float rpart[128][2];
  f32x4 acc[4][4];
#pragma unroll
  for (int i = 0; i < 4; ++i)
#pragma unroll
    for (int j = 0; j < 4; ++j) acc[i][j] = (f32x4){0.f, 0.f, 0.f, 0.f};
  int lin = swiz(blockIdx.y * 25 + blockIdx.x, 25 * NB);
  const int b = lin / 25;
  const int tM = (lin % 25) / 5, tN = lin % 5;
  const unsigned short* A = qb + (size_t)b * SEQ * DIM;
  const unsigned short* B = kb + (size_t)b * SEQ * DIM;
  gemm_core(smem, A, DIM, SEQ - 1, tM * TILE, B, DIM, SEQ - 1, tN * TILE, DIM, acc);

  const int t = threadIdx.x, lane = t & 63, wave = t >> 6;
  const int wr = (wave >> 1) * 64, wc = (wave & 1) * 64;
  const int l15 = lane & 15, quad = lane >> 4;

  // exp2 (no max subtraction needed: |logit*scale| <= ~6), zero pad cols
#pragma unroll
  for (int i = 0; i < 4; ++i)
#pragma unroll
    for (int j = 0; j < 4; ++j) {
      int ng = tN * TILE + wc + j * 16 + l15;
#pragma unroll
      for (int r = 0; r < 4; ++r) {
        float e = exp2f(acc[i][j][r] * KC);
        acc[i][j][r] = (ng < SEQ) ? e : 0.f;
      }
    }
  // row partials: each thread's 16 rows, sum over its 16 cols, reduce over l15
#pragma unroll
  for (int i = 0; i < 4; ++i)
#pragma unroll
    for (int r = 0; r < 4; ++r) {
      float p = acc[i][0][r] + acc[i][1][r] + acc[i][2][r] + acc[i][3][r];
      p += __shfl_xor(p, 1); p += __shfl_xor(p, 2);
      p += __shfl_xor(p, 4); p += __shfl_xor(p, 8);
      if (l15 == 0) rpart[wr + i * 16 + quad * 4 + r][wave & 1] = p;
    }
  __syncthreads();
  if (t < 128) {
    int row = tM * TILE + t;
    if (row < SEQ)
      part[((size_t)b * 5 + tN) * SEQP + row] = rpart[t][0] + rpart[t][1];
  }
  // stage bf16 [m][n] and wide-store (skip pad rows >= SEQ)
#pragma unroll
  for (int i = 0; i < 4; ++i)
#pragma unroll
    for (int j = 0; j < 4; ++j)
#pragma unroll
      for (int r = 0; r < 4; ++r) {
        int m = wr + i * 16 + quad * 4 + r, n = wc + j * 16 + l15;
        smem[m * TILE + (n ^ ((m & 7) << 3))] = f2bf(acc[i][j][r]);
      }
  __syncthreads();
  unsigned short* Pb = Pt + (size_t)b * SEQP * SEQP;
#pragma unroll
  for (int s = 0; s < 8; ++s) {
    int idx = t + s * 256, rr = idx >> 4, seg = idx & 15;
    int m = tM * TILE + rr;
    if (m < SEQ) {
      ushort8v v = *(const ushort8v*)(smem + rr * TILE + ((seg * 8) ^ ((rr & 7) << 3)));
      *(ushort8v*)(Pb + (size_t)m * SEQP + tN * TILE + seg * 8) = v;
    }
  }
}

// yT[c][n] = (1/l_n) sum_k vt[c,k] * Pt[n,k]  — operand-swapped PV.
// tC==0 blocks also write token_attn for their token range.
__global__ __launch_bounds__(256, 2) void k_pv(
    const unsigned short* __restrict__ Pt, const unsigned short* __restrict__ vt,
    const float* __restrict__ part, unsigned short* __restrict__ yf,
    float* __restrict__ tok) {
  __shared__ unsigned short smem[2 * TILE * BK];
  __shared__ float linv[128];
  f32x4 acc[4][4];
#pragma unroll
  for (int i = 0; i < 4; ++i)
#pragma unroll
    for (int j = 0; j < 4; ++j) acc[i][j] = (f32x4){0.f, 0.f, 0.f, 0.f};
  int lin = swiz(blockIdx.y * 30 + blockIdx.x, 30 * NB);
  const int b = lin / 30;
  const int tC = (lin % 30) / 5, tT = lin % 5;
  gemm_core(smem, vt + (size_t)b * SEQP, VTLD, DIM - 1, tC * TILE,
            Pt + (size_t)b * SEQP * SEQP, SEQP, SEQP - 1, tT * TILE, SEQP, acc);

  const int t = threadIdx.x, lane = t & 63, wave = t >> 6;
  const int wr = (wave >> 1) * 64, wc = (wave & 1) * 64;
  const int l15 = lane & 15, quad = lane >> 4;

  if (t < 128) {
    int row = tT * TILE + t;                          // token (P row)
    if (row < SEQ) {
      const float* pp = part + (size_t)b * 5 * SEQP + row;
      float s = pp[0] + pp[SEQP] + pp[2 * SEQP] + pp[3 * SEQP] + pp[4 * SEQP];
      linv[t] = 1.0f / s;        // exp sums are strictly positive
    } else linv[t] = 0.0f;       // pad tokens: keep math finite
  }
  __syncthreads();

  // stage row-major [m=channel][n=token], normalized per column
#pragma unroll
  for (int j = 0; j < 4; ++j) {
    float ln = linv[wc + j * 16 + l15];
#pragma unroll
    for (int i = 0; i < 4; ++i)
#pragma unroll
      for (int r = 0; r < 4; ++r) {
        int m = wr + i * 16 + quad * 4 + r, n = wc + j * 16 + l15;
        smem[m * TILE + (n ^ ((m & 7) << 3))] = f2bf(acc[i][j][r] * ln);
      }
  }
  __syncthreads();

  const int rowc = t >> 1, h = t & 1;
  const int c = tC * TILE + rowc;
  const int sw = (rowc & 7) << 3;
  unsigned short* yrow = yf + ((size_t)b * DIM + c) * SEQ;
  int n0 = tT * TILE + h * 64;
  int nend = n0 + 64; if (nend > SEQ) nend = SEQ;
  int n = n0;
  // phase-align to 8B: ((b*768+c)*577 + n)*2 % 8 == 0  <=>  (c+n) % 4 == 0
  while (n < nend && ((c + n) & 3)) { yrow[n] = smem[rowc * TILE + ((n - tT * TILE) ^ sw)]; ++n; }
  for (; n + 4 <= nend; n += 4) {
    ushort4v v;
#pragma unroll
    for (int e = 0; e < 4; ++e) v[e] = smem[rowc * TILE + ((n + e - tT * TILE) ^ sw)];
    *(ushort4v*)(yrow + n) = v;
  }
  for (; n < nend; ++n) yrow[n] = smem[rowc * TILE + ((n - tT * TILE) ^ sw)];

  if (tC == 0 && t < 128) {
    const float* pp = part + (size_t)b * 5 * SEQP;
    float inv0 = 1.0f / (pp[0] + pp[SEQP] + pp[2 * SEQP] + pp[3 * SEQP] + pp[4 * SEQP]);
    int nt = tT * TILE + t;
    if (nt >= 1 && nt < SEQ)
      tok[(size_t)b * (SEQ - 1) + nt - 1] =
          bf2f(Pt[(size_t)b * SEQP * SEQP + nt]) * inv0;
  }
}

// out = (yT flat as [18464,768]) @ w_proj^T + b_proj, LDS-staged fp32 epilogue
__global__ __launch_bounds__(256, 2) void k_proj(
    const unsigned short* __restrict__ yf, const unsigned short* __restrict__ wpb,
    const float* __restrict__ bproj, float* __restrict__ out) {
  __shared__ unsigned short smem[2 * TILE * BK];
  f32x4 acc[4][4];
#pragma unroll
  for (int i = 0; i < 4; ++i)
#pragma unroll
    for (int j = 0; j < 4; ++j) acc[i][j] = (f32x4){0.f, 0.f, 0.f, 0.f};
  int lin = swiz(blockIdx.y * 6 + blockIdx.x, 6 * 145);
  const int tM = lin / 6, tN = lin % 6;
  gemm_core(smem, yf, DIM, MTOT - 1, tM * TILE, wpb, DIM, DIM - 1, tN * TILE, DIM, acc);

  const int t = threadIdx.x, lane = t & 63, wave = t >> 6;
  const int wc = (wave & 1) * 64;
  const int l15 = lane & 15, quad = lane >> 4;
  float* smem32 = (float*)smem;                      // [64][128] fp32 = 32 KB
  const int wquad = wave >> 1;

#pragma unroll
  for (int p = 0; p < 2; ++p) {
    if (wquad == p) {
#pragma unroll
      for (int j = 0; j < 4; ++j) {
        int n = wc + j * 16 + l15;
        float bias = bproj[tN * TILE + n];
#pragma unroll
        for (int i = 0; i < 4; ++i)
#pragma unroll
          for (int r = 0; r < 4; ++r)
            smem32[(i * 16 + quad * 4 + r) * TILE + n] = acc[i][j][r] + bias;
      }
    }
    __syncthreads();
#pragma unroll
    for (int s = 0; s < 8; ++s) {
      int idx = t + s * 256;
      int rloc = idx >> 5, col4 = idx & 31;
      int m = tM * TILE + p * 64 + rloc;
      if (m < MTOT)
        ((float4*)(out + (size_t)m * DIM + tN * TILE))[col4] =
            ((const float4*)(smem32 + rloc * TILE))[col4];
    }
    __syncthreads();
  }
}

// ---------------------------------------------------------------------------
extern "C" void kernel_launch(void* const* d_in, const int* in_sizes, int n_in,
                              void* d_out, int out_size, void* d_ws, size_t ws_size,
                              hipStream_t stream) {
  const float* x     = (const float*)d_in[0];   // [32,577,768]
  const float* wqkv  = (const float*)d_in[1];   // [2304,768]
  const float* wproj = (const float*)d_in[2];   // [768,768]
  const float* bproj = (const float*)d_in[3];   // [768]
  float* out = (float*)d_out;
  float* tok = out + (size_t)NB * SEQ * DIM;    // token_attn tail

  char* ws = (char*)d_ws;
  unsigned short* xb    = (unsigned short*)(ws + 0);           //  28,360,704
  unsigned short* wqkvb = (unsigned short*)(ws + 28360704);    //   3,538,944
  unsigned short* wprojb= (unsigned short*)(ws + 31899648);    //   1,179,648
  unsigned short* qb    = (unsigned short*)(ws + 33079296);    //  28,360,704
  unsigned short* kb    = (unsigned short*)(ws + 61440000);    //  28,360,704
  unsigned short* vt    = (unsigned short*)(ws + 89800704);    //  31,457,280  [768][32*640]
  unsigned short* Pt    = (unsigned short*)(ws + 121257984);   //  26,214,400  [32][640][640]
  float*          part  = (float*)         (ws + 147472384);   //     409,600  [32][5][640]
  unsigned short* yf    = (unsigned short*)(ws + 147881984);   //  28,360,704  [32][768][577]
  // total: 176,242,688 bytes

  k_cvt3<<<16152, 256, 0, stream>>>(x, wqkv, wproj, xb, wqkvb, wprojb);
  k_qkv_qk<<<dim3(12, 145), 256, 0, stream>>>(xb, wqkvb, qb, kb);
  k_logits<<<dim3(25, NB), 256, 0, stream>>>(qb, kb, Pt, part);
  k_qkv_v<<<dim3(6, 160), 256, 0, stream>>>(xb, wqkvb, vt);
  k_pv<<<dim3(30, NB), 256, 0, stream>>>(Pt, vt, part, yf, tok);
  k_proj<<<dim3(6, 145), 256, 0, stream>>>(yf, wprojb, bproj, out);
}